// Round 7
// baseline (307.742 us; speedup 1.0000x reference)
//
#include <hip/hip_runtime.h>
#include <hip/hip_bf16.h>

typedef __bf16 bf16;
typedef __bf16 bf16x4 __attribute__((ext_vector_type(4)));
typedef __bf16 bf16x8 __attribute__((ext_vector_type(8)));
typedef float  f32x4  __attribute__((ext_vector_type(4)));

#define DEV static __device__ __forceinline__

static constexpr int Bsz = 4, T = 2048, C = 1024, H = 16;
static constexpr int M  = Bsz * T;   // 8192
static constexpr int N1 = 3 * C;     // 3072
static constexpr float SM_SCALE = 0.125f;  // D^-0.5 = 2^-3, exact in bf16

// async global->LDS, 16B per lane. LDS dest: wave-uniform base + lane*16B;
// global source address is PER-LANE (enables pre-swizzled sources, m173).
DEV void gload16(const bf16* g, const bf16* l) {
  __builtin_amdgcn_global_load_lds(
      (const __attribute__((address_space(1))) void*)g,
      (__attribute__((address_space(3))) void*)l, 16, 0, 0);
}

// ---------------------------------------------------------------------------
// fp32 -> bf16 convert (vectorized, memory-bound)
// ---------------------------------------------------------------------------
__launch_bounds__(256)
__global__ void convert_kernel(const float* __restrict__ in, bf16* __restrict__ out) {
  const size_t i = ((size_t)blockIdx.x * 256 + threadIdx.x) * 8;
  f32x4 a = *(const f32x4*)(in + i);
  f32x4 b = *(const f32x4*)(in + i + 4);
  *(bf16x4*)(out + i)     = __builtin_convertvector(a, bf16x4);
  *(bf16x4*)(out + i + 4) = __builtin_convertvector(b, bf16x4);
}

// ---------------------------------------------------------------------------
// Transpose + fp32->bf16 convert:  in[K][N] (fp32) -> out[N][K] (bf16)
// ---------------------------------------------------------------------------
__launch_bounds__(256)
__global__ void transpose_conv_kernel(const float* __restrict__ in,
                                      bf16* __restrict__ out, int K, int N) {
  __shared__ float t[32][33];
  const int n0 = blockIdx.x * 32, k0 = blockIdx.y * 32;
  const int tx = threadIdx.x & 31, ty = threadIdx.x >> 5;  // ty in 0..7
#pragma unroll
  for (int j = 0; j < 4; ++j)
    t[ty + j * 8][tx] = in[(size_t)(k0 + ty + j * 8) * N + n0 + tx];
  __syncthreads();
#pragma unroll
  for (int j = 0; j < 4; ++j)
    out[(size_t)(n0 + ty + j * 8) * K + k0 + tx] = (bf16)t[tx][ty + j * 8];
}

// ---------------------------------------------------------------------------
// GEMM (m97 structure) + bijective XCD m-chunking (each XCD owns a
// contiguous m-range -> A-panel L2-resident).  V_SPLIT (GEMM1 only):
// cols < 2C  -> row-major Out[row][col], row stride 2C (Q,K)
// cols >= 2C -> V written TRANSPOSED to vt[b][h][d][t] (t-contiguous bf16x4)
// so attention can stage V^T with zero shuffle work.
// ---------------------------------------------------------------------------
template <bool OUT_BF16, bool V_SPLIT>
__launch_bounds__(256)
__global__ void gemm_kernel(const bf16* __restrict__ A,
                            const bf16* __restrict__ Bt,
                            const float* __restrict__ bias,
                            void* __restrict__ Out, bf16* __restrict__ vt,
                            int Ndim, int Kdim) {
  __shared__ bf16 lds_a[128 * 64];
  __shared__ bf16 lds_b[128 * 64];
  const int tid = threadIdx.x;
  const int l = tid & 63, wid = tid >> 6;
  const int wm = wid >> 1, wn = wid & 1;
  const int lr = l & 15, lh = l >> 4;
  // XCD m-chunking: gx % 8 == 0 for all our grids (gx = 64).
  const int gx = gridDim.x, cpx = gx >> 3;
  const int L = blockIdx.y * gx + blockIdx.x;
  const int xcd = L & 7, q = L >> 3;
  const int m0 = (xcd * cpx + (q & (cpx - 1))) * 128;
  const int n0 = (q / cpx) * 128;
  const int r8 = l >> 3, g8 = (l & 7) * 8;

  f32x4 acc[4][4] = {};

  for (int k0 = 0; k0 < Kdim; k0 += 64) {
    __syncthreads();
#pragma unroll
    for (int i = 0; i < 4; ++i) {
      const int c = wid * 4 + i;
      const int row = c * 8 + r8;
      gload16(A  + (size_t)(m0 + row) * Kdim + k0 + g8, &lds_a[c * 512]);
      gload16(Bt + (size_t)(n0 + row) * Kdim + k0 + g8, &lds_b[c * 512]);
    }
    __syncthreads();
#pragma unroll
    for (int kk = 0; kk < 2; ++kk) {
      bf16x8 af[4], bfr[4];
#pragma unroll
      for (int mi = 0; mi < 4; ++mi)
        af[mi] = *(const bf16x8*)&lds_a[(wm * 64 + mi * 16 + lr) * 64 + kk * 32 + lh * 8];
#pragma unroll
      for (int ni = 0; ni < 4; ++ni)
        bfr[ni] = *(const bf16x8*)&lds_b[(wn * 64 + ni * 16 + lr) * 64 + kk * 32 + lh * 8];
#pragma unroll
      for (int mi = 0; mi < 4; ++mi)
#pragma unroll
        for (int ni = 0; ni < 4; ++ni)
          acc[mi][ni] = __builtin_amdgcn_mfma_f32_16x16x32_bf16(
              af[mi], bfr[ni], acc[mi][ni], 0, 0, 0);
    }
  }
  if (V_SPLIT && n0 >= 2 * C) {
    // V columns: write transposed vt[b][h][d][t]; t = row, contiguous in r.
    const int b = m0 >> 11, tb = (m0 & 2047) + wm * 64;
#pragma unroll
    for (int ni = 0; ni < 4; ++ni) {
      const int col = n0 - 2 * C + wn * 64 + ni * 16 + lr;  // 0..1023
      const int hh = col >> 6, dd = col & 63;
      const float bv = bias[2 * C + col];
      bf16* vdst = vt + ((size_t)((b * H + hh) * 64 + dd)) * T + tb + lh * 4;
#pragma unroll
      for (int mi = 0; mi < 4; ++mi) {
        bf16x4 p4;
#pragma unroll
        for (int r = 0; r < 4; ++r) p4[r] = (bf16)(acc[mi][ni][r] + bv);
        *(bf16x4*)&vdst[mi * 16] = p4;
      }
    }
  } else {
#pragma unroll
    for (int ni = 0; ni < 4; ++ni) {
      const int col = n0 + wn * 64 + ni * 16 + lr;
      const float bv = bias[col];
#pragma unroll
      for (int mi = 0; mi < 4; ++mi) {
#pragma unroll
        for (int r = 0; r < 4; ++r) {
          const int row = m0 + wm * 64 + mi * 16 + lh * 4 + r;
          const float v = acc[mi][ni][r] + bv;
          if (OUT_BF16)
            ((bf16*)Out)[(size_t)row * Ndim + col] = (bf16)v;
          else
            ((float*)Out)[(size_t)row * Ndim + col] = v;
        }
      }
    }
  }
}

// ---------------------------------------------------------------------------
// Flash attention (causal), swapped QK^T, balanced persistent grid (1024
// blocks x 33 tile-steps), double-buffered K/V staged DIRECTLY via
// global_load_lds with inverse-swizzled per-lane global sources:
// LDS slot (row, chunk c) <- global chunk c ^ swz(row). LDS content and all
// read paths are bit-identical to round 6; the VGPR round-trip, the 16-store
// V scatter and their ~60 VALU addr ops are gone. V comes pre-transposed
// from GEMM1 (vt[b][h][d][t]).
// ---------------------------------------------------------------------------
DEV int vswz(int d, int key) {  // elem index into V^T tile [64 d][64 key]
  return (d * 64 + key) ^ ((((d & 7) ^ (d >> 3)) & 7) << 3);
}

__launch_bounds__(256)
__global__ void attn_kernel(const bf16* __restrict__ qk,
                            const bf16* __restrict__ vt,
                            bf16* __restrict__ out) {
  __shared__ bf16 lds_k[2][64 * 64];
  __shared__ bf16 lds_vt[2][64 * 64];
  __shared__ bf16 lds_p[4][16 * 64];
  const int tid = threadIdx.x, l = tid & 63, w = tid >> 6;
  const int lr = l & 15, lh = l >> 4;
  const int p = blockIdx.x;
  const int bh = p >> 4, jj = p & 15;
  const int b = bh >> 4, h = bh & 15;
  const size_t RS = 2 * C;  // qk row stride (elems)
  const bf16* base  = qk + (size_t)b * T * RS;
  const bf16* kbase = base + C + h * 64;
  const bf16* vth   = vt + (size_t)bh * 64 * T;
  bf16* op = out + (size_t)b * T * C + h * 64;
  // staging: slot s = i*256+tid covers (row = s>>3, chunk c = s&7)
  const int r1 = tid >> 3, cc = tid & 7;
  const int kc = cc ^ (r1 & 7);  // K: chunk c ^ (row&7); row&7 == r1&7 for both i

  for (int it = 0; it < 2; ++it) {
    const int qt = it ? jj : 31 - jj;   // long item first
    const int q16 = qt * 64 + w * 16;
    // Q fragments (regs), pre-scaled by 2^-3 (exact in bf16)
    bf16x8 qf[2];
#pragma unroll
    for (int kk = 0; kk < 2; ++kk) {
      bf16x8 qv = *(const bf16x8*)(base + (size_t)(q16 + lr) * RS + h * 64 + kk * 32 + lh * 8);
#pragma unroll
      for (int j = 0; j < 8; ++j) qf[kk][j] = (bf16)((float)qv[j] * SM_SCALE);
    }

    float mq = -__builtin_inff(), lq = 0.f;   // softmax state for q = lr
    f32x4 o[4] = {};

    // ---- prologue: stage tile 0 into buf 0 (async)
    __syncthreads();  // previous item's readers done before overwrite
#pragma unroll
    for (int i = 0; i < 2; ++i) {
      const int row = i * 32 + r1;
      gload16(kbase + (size_t)row * RS + kc * 8, &lds_k[0][i * 2048 + w * 512]);
      const int vc = cc ^ (((r1 & 7) ^ (i * 4 + (r1 >> 3))) & 7);
      gload16(vth + (size_t)row * T + vc * 8, &lds_vt[0][i * 2048 + w * 512]);
    }
    __syncthreads();  // vmcnt(0) drained here by compiler

    int buf = 0;
    for (int kt = 0; kt <= qt; ++kt) {
      const bf16* kb = &lds_k[buf][0];
      const bf16* vb = &lds_vt[buf][0];
      // ---- issue async prefetch of tile kt+1 into buf^1
      if (kt < qt) {
        const int nb = buf ^ 1;
#pragma unroll
        for (int i = 0; i < 2; ++i) {
          const int row = i * 32 + r1;
          gload16(kbase + (size_t)((kt + 1) * 64 + row) * RS + kc * 8,
                  &lds_k[nb][i * 2048 + w * 512]);
          const int vc = cc ^ (((r1 & 7) ^ (i * 4 + (r1 >> 3))) & 7);
          gload16(vth + (size_t)row * T + (kt + 1) * 64 + vc * 8,
                  &lds_vt[nb][i * 2048 + w * 512]);
        }
      }

      // ---- S^T = K (Q*scale)^T : s4[kn][r] = S[key=kn*16+lh*4+r][q=lr]
      f32x4 s4[4] = {};
      __builtin_amdgcn_s_setprio(1);
#pragma unroll
      for (int kk = 0; kk < 2; ++kk) {
#pragma unroll
        for (int kn = 0; kn < 4; ++kn) {
          const int key = kn * 16 + lr;
          bf16x8 kf = *(const bf16x8*)&kb[(key * 64 + kk * 32 + lh * 8) ^ ((key & 7) << 3)];
          s4[kn] = __builtin_amdgcn_mfma_f32_16x16x32_bf16(kf, qf[kk], s4[kn], 0, 0, 0);
        }
      }
      __builtin_amdgcn_s_setprio(0);
      // ---- causal mask (diagonal tile only): mask key_local > q_local
      if (kt == qt) {
        const int qloc = w * 16 + lr;
#pragma unroll
        for (int kn = 0; kn < 4; ++kn)
#pragma unroll
          for (int r = 0; r < 4; ++r)
            if ((kn * 16 + lh * 4 + r) > qloc) s4[kn][r] = -__builtin_inff();
      }
      // ---- online softmax: in-lane over 16 keys + 2 shfl (q = lr)
      float pm = s4[0][0];
#pragma unroll
      for (int kn = 0; kn < 4; ++kn)
#pragma unroll
        for (int r = 0; r < 4; ++r) pm = fmaxf(pm, s4[kn][r]);
      pm = fmaxf(pm, __shfl_xor(pm, 16));
      pm = fmaxf(pm, __shfl_xor(pm, 32));
      const float mnew = fmaxf(mq, pm);
      const float alpha_q = __expf(mq - mnew);
      mq = mnew;
      float ssum = 0.f;
#pragma unroll
      for (int kn = 0; kn < 4; ++kn)
#pragma unroll
        for (int r = 0; r < 4; ++r) {
          const float p2 = __expf(s4[kn][r] - mnew);
          s4[kn][r] = p2;
          ssum += p2;
        }
      // ---- P -> LDS early (lgkm drain overlaps shuffles/rescale below)
#pragma unroll
      for (int kn = 0; kn < 4; ++kn) {
        bf16x4 pb;
#pragma unroll
        for (int r = 0; r < 4; ++r) pb[r] = (bf16)s4[kn][r];
        *(bf16x4*)&lds_p[w][(lr * 64 + kn * 16 + lh * 4) ^ ((lr & 7) << 3)] = pb;
      }
      ssum += __shfl_xor(ssum, 16);
      ssum += __shfl_xor(ssum, 32);
      lq = lq * alpha_q + ssum;
      // ---- rescale O (O layout: q = lh*4+r)
      float al[4];
#pragma unroll
      for (int r = 0; r < 4; ++r) al[r] = __shfl(alpha_q, lh * 4 + r);
#pragma unroll
      for (int ni = 0; ni < 4; ++ni)
#pragma unroll
        for (int r = 0; r < 4; ++r) o[ni][r] *= al[r];
      // ---- O += P V
      __builtin_amdgcn_s_setprio(1);
#pragma unroll
      for (int kk = 0; kk < 2; ++kk) {
        bf16x8 pf = *(const bf16x8*)&lds_p[w][(lr * 64 + kk * 32 + lh * 8) ^ ((lr & 7) << 3)];
#pragma unroll
        for (int ni = 0; ni < 4; ++ni) {
          const int d = ni * 16 + lr;
          bf16x8 vf = *(const bf16x8*)&vb[vswz(d, kk * 32 + lh * 8)];
          o[ni] = __builtin_amdgcn_mfma_f32_16x16x32_bf16(pf, vf, o[ni], 0, 0, 0);
        }
      }
      __builtin_amdgcn_s_setprio(0);

      // ---- barrier drains prefetch (vmcnt(0) at s_barrier), swap
      if (kt < qt) {
        __syncthreads();
        buf ^= 1;
      }
    }
    // ---- epilogue: reciprocal of lsum for O's q-rows, store [B*T][C]
    float lrec[4];
#pragma unroll
    for (int r = 0; r < 4; ++r) lrec[r] = 1.0f / __shfl(lq, lh * 4 + r);
#pragma unroll
    for (int ni = 0; ni < 4; ++ni)
#pragma unroll
      for (int r = 0; r < 4; ++r) {
        const int qrow = q16 + lh * 4 + r;
        op[(size_t)qrow * C + ni * 16 + lr] = (bf16)(o[ni][r] * lrec[r]);
      }
  }
}

// ---------------------------------------------------------------------------
extern "C" void kernel_launch(void* const* d_in, const int* in_sizes, int n_in,
                              void* d_out, int out_size, void* d_ws, size_t ws_size,
                              hipStream_t stream) {
  const float* x     = (const float*)d_in[0];
  const float* Wqkv  = (const float*)d_in[1];
  const float* bqkv  = (const float*)d_in[2];
  const float* Wproj = (const float*)d_in[3];
  const float* bproj = (const float*)d_in[4];
  float* out = (float*)d_out;

  char* ws = (char*)d_ws;
  bf16* qk       = (bf16*)(ws);             // 8192*2048*2 = 33554432 B (Q,K)
  bf16* vt       = (bf16*)(ws + 33554432);  // 64*64*2048*2 = 16777216 B (V^T)
  bf16* wqkvt    = (bf16*)(ws + 50331648);  // 3072*1024*2 =  6291456 B
  bf16* wprojt   = (bf16*)(ws + 56623104);  // 1024*1024*2 =  2097152 B
  bf16* attn_out = (bf16*)(ws + 58720256);  // 8192*1024*2 = 16777216 B (total 72 MiB)
  bf16* x_bf16   = attn_out;  // aliased: x_bf16 dead before attn writes attn_out

  convert_kernel<<<dim3(M * C / (256 * 8)), 256, 0, stream>>>(x, x_bf16);
  transpose_conv_kernel<<<dim3(N1 / 32, C / 32), 256, 0, stream>>>(Wqkv, wqkvt, C, N1);
  transpose_conv_kernel<<<dim3(C / 32, C / 32), 256, 0, stream>>>(Wproj, wprojt, C, C);
  // QKV projection: Q,K -> qk[M][2C]; V -> vt[b][h][d][t]
  gemm_kernel<true, true><<<dim3(M / 128, N1 / 128), 256, 0, stream>>>(
      x_bf16, wqkvt, bqkv, qk, vt, 2 * C, C);
  attn_kernel<<<dim3(Bsz * H * 16), 256, 0, stream>>>(qk, vt, attn_out);
  gemm_kernel<false, false><<<dim3(M / 128, C / 128), 256, 0, stream>>>(
      attn_out, wprojt, bproj, out, nullptr, C, C);
}

// Round 8
// 291.931 us; speedup vs baseline: 1.0542x; 1.0542x over previous
//
#include <hip/hip_runtime.h>
#include <hip/hip_bf16.h>

typedef __bf16 bf16;
typedef __bf16 bf16x4 __attribute__((ext_vector_type(4)));
typedef __bf16 bf16x8 __attribute__((ext_vector_type(8)));
typedef float  f32x4  __attribute__((ext_vector_type(4)));

#define DEV static __device__ __forceinline__

static constexpr int Bsz = 4, T = 2048, C = 1024, H = 16;
static constexpr int M  = Bsz * T;   // 8192
static constexpr int N1 = 3 * C;     // 3072
static constexpr float SM_SCALE = 0.125f;  // D^-0.5 = 2^-3, exact in bf16

// async global->LDS, 16B per lane. LDS dest: wave-uniform base + lane*16B;
// global source address is PER-LANE (enables pre-swizzled sources, m173).
DEV void gload16(const bf16* g, const bf16* l) {
  __builtin_amdgcn_global_load_lds(
      (const __attribute__((address_space(1))) void*)g,
      (__attribute__((address_space(3))) void*)l, 16, 0, 0);
}

// ---------------------------------------------------------------------------
// fp32 -> bf16 convert (vectorized, memory-bound)
// ---------------------------------------------------------------------------
__launch_bounds__(256)
__global__ void convert_kernel(const float* __restrict__ in, bf16* __restrict__ out) {
  const size_t i = ((size_t)blockIdx.x * 256 + threadIdx.x) * 8;
  f32x4 a = *(const f32x4*)(in + i);
  f32x4 b = *(const f32x4*)(in + i + 4);
  *(bf16x4*)(out + i)     = __builtin_convertvector(a, bf16x4);
  *(bf16x4*)(out + i + 4) = __builtin_convertvector(b, bf16x4);
}

// ---------------------------------------------------------------------------
// Transpose + fp32->bf16 convert:  in[K][N] (fp32) -> out[N][K] (bf16)
// ---------------------------------------------------------------------------
__launch_bounds__(256)
__global__ void transpose_conv_kernel(const float* __restrict__ in,
                                      bf16* __restrict__ out, int K, int N) {
  __shared__ float t[32][33];
  const int n0 = blockIdx.x * 32, k0 = blockIdx.y * 32;
  const int tx = threadIdx.x & 31, ty = threadIdx.x >> 5;  // ty in 0..7
#pragma unroll
  for (int j = 0; j < 4; ++j)
    t[ty + j * 8][tx] = in[(size_t)(k0 + ty + j * 8) * N + n0 + tx];
  __syncthreads();
#pragma unroll
  for (int j = 0; j < 4; ++j)
    out[(size_t)(n0 + ty + j * 8) * K + k0 + tx] = (bf16)t[tx][ty + j * 8];
}

// ---------------------------------------------------------------------------
// GEMM (m97 structure): Out = A @ Bt^T + bias.  V_SPLIT (GEMM1): V columns
// written transposed to vt[b][h][d][t] so attention stages V^T directly.
// (plain block mapping restored — XCD chunking was the round-7 regression)
// ---------------------------------------------------------------------------
template <bool OUT_BF16, bool V_SPLIT>
__launch_bounds__(256)
__global__ void gemm_kernel(const bf16* __restrict__ A,
                            const bf16* __restrict__ Bt,
                            const float* __restrict__ bias,
                            void* __restrict__ Out, bf16* __restrict__ vt,
                            int Ndim, int Kdim) {
  __shared__ bf16 lds_a[128 * 64];
  __shared__ bf16 lds_b[128 * 64];
  const int tid = threadIdx.x;
  const int l = tid & 63, wid = tid >> 6;
  const int wm = wid >> 1, wn = wid & 1;
  const int lr = l & 15, lh = l >> 4;
  const int m0 = blockIdx.x * 128, n0 = blockIdx.y * 128;
  const int r8 = l >> 3, g8 = (l & 7) * 8;

  f32x4 acc[4][4] = {};

  for (int k0 = 0; k0 < Kdim; k0 += 64) {
    __syncthreads();
#pragma unroll
    for (int i = 0; i < 4; ++i) {
      const int c = wid * 4 + i;
      const int row = c * 8 + r8;
      gload16(A  + (size_t)(m0 + row) * Kdim + k0 + g8, &lds_a[c * 512]);
      gload16(Bt + (size_t)(n0 + row) * Kdim + k0 + g8, &lds_b[c * 512]);
    }
    __syncthreads();
#pragma unroll
    for (int kk = 0; kk < 2; ++kk) {
      bf16x8 af[4], bfr[4];
#pragma unroll
      for (int mi = 0; mi < 4; ++mi)
        af[mi] = *(const bf16x8*)&lds_a[(wm * 64 + mi * 16 + lr) * 64 + kk * 32 + lh * 8];
#pragma unroll
      for (int ni = 0; ni < 4; ++ni)
        bfr[ni] = *(const bf16x8*)&lds_b[(wn * 64 + ni * 16 + lr) * 64 + kk * 32 + lh * 8];
#pragma unroll
      for (int mi = 0; mi < 4; ++mi)
#pragma unroll
        for (int ni = 0; ni < 4; ++ni)
          acc[mi][ni] = __builtin_amdgcn_mfma_f32_16x16x32_bf16(
              af[mi], bfr[ni], acc[mi][ni], 0, 0, 0);
    }
  }
  if (V_SPLIT && n0 >= 2 * C) {
    const int b = m0 >> 11, tb = (m0 & 2047) + wm * 64;
#pragma unroll
    for (int ni = 0; ni < 4; ++ni) {
      const int col = n0 - 2 * C + wn * 64 + ni * 16 + lr;  // 0..1023
      const int hh = col >> 6, dd = col & 63;
      const float bv = bias[2 * C + col];
      bf16* vdst = vt + ((size_t)((b * H + hh) * 64 + dd)) * T + tb + lh * 4;
#pragma unroll
      for (int mi = 0; mi < 4; ++mi) {
        bf16x4 p4;
#pragma unroll
        for (int r = 0; r < 4; ++r) p4[r] = (bf16)(acc[mi][ni][r] + bv);
        *(bf16x4*)&vdst[mi * 16] = p4;
      }
    }
  } else {
#pragma unroll
    for (int ni = 0; ni < 4; ++ni) {
      const int col = n0 + wn * 64 + ni * 16 + lr;
      const float bv = bias[col];
#pragma unroll
      for (int mi = 0; mi < 4; ++mi) {
#pragma unroll
        for (int r = 0; r < 4; ++r) {
          const int row = m0 + wm * 64 + mi * 16 + lh * 4 + r;
          const float v = acc[mi][ni][r] + bv;
          if (OUT_BF16)
            ((bf16*)Out)[(size_t)row * Ndim + col] = (bf16)v;
          else
            ((float*)Out)[(size_t)row * Ndim + col] = v;
        }
      }
    }
  }
}

// ---------------------------------------------------------------------------
// Flash attention (causal), KVBLK=128, Q-block=128, 8 waves (512 thr).
// Round-7 diagnosis: 8.1k cy wall per tile-step vs ~3.2k cy issue work ->
// latency-chain-bound. Fix: 2x work per step (32 MFMA, 32 exp per wave),
// steps 33 -> 17 (pair J and 15-J: (J+1)+(16-J)=17, all 512 blocks equal;
// 2 blocks/CU exactly at 80KB LDS). Swapped QK^T softmax unchanged.
// V^T tile [64 d][128 key] with 3-bit XOR chunk swizzle, staged linearly by
// global_load_lds from inverse-swizzled sources (rule 21 both-sides).
// P-LDS roundtrip reused in two 64-key halves (2KB/wave unchanged).
// ---------------------------------------------------------------------------
DEV int vswz3(int d) { return (d & 7) ^ ((d >> 3) & 7); }

__launch_bounds__(512, 4)
__global__ void attn_kernel(const bf16* __restrict__ qk,
                            const bf16* __restrict__ vt,
                            bf16* __restrict__ out) {
  __shared__ bf16 lds_k[2][128 * 64];   // 32 KB
  __shared__ bf16 lds_vt[2][64 * 128];  // 32 KB
  __shared__ bf16 lds_p[8][16 * 64];    // 16 KB
  const int tid = threadIdx.x, l = tid & 63, w = tid >> 6;  // w: 0..7
  const int lr = l & 15, lh = l >> 4;
  const int p = blockIdx.x;
  const int bh = p >> 3, jj = p & 7;
  const int b = bh >> 4, h = bh & 15;
  const size_t RS = 2 * C;  // qk row stride (elems)
  const bf16* base  = qk + (size_t)b * T * RS;
  const bf16* kbase = base + C + h * 64;
  const bf16* vth   = vt + (size_t)bh * 64 * T;
  bf16* op = out + (size_t)b * T * C + h * 64;
  // staging decomposition (512 threads, 2 instrs each for K and V):
  const int r1 = tid >> 3, cc = tid & 7;   // K: row group, chunk
  const int kc = cc ^ (r1 & 7);            // K source chunk (inv-swizzle)
  const int dV = tid >> 4, cV = tid & 15;  // V: d group, chunk (16/row)

  auto STAGE = [&](int nb, int kt) {
#pragma unroll
    for (int i = 0; i < 2; ++i) {
      const int rowK = i * 64 + r1;
      gload16(kbase + (size_t)(kt * 128 + rowK) * RS + kc * 8,
              &lds_k[nb][i * 4096 + w * 512]);
      const int d = i * 32 + dV;
      const int vc = (cV & 8) | (((cV & 7) ^ vswz3(d)) & 7);
      gload16(vth + (size_t)d * T + kt * 128 + vc * 8,
              &lds_vt[nb][i * 4096 + w * 512]);
    }
  };

  for (int it = 0; it < 2; ++it) {
    const int J = it ? jj : 15 - jj;   // long item first
    const int q16 = J * 128 + w * 16;
    // Q fragments (regs), pre-scaled by 2^-3 (exact in bf16)
    bf16x8 qf[2];
#pragma unroll
    for (int kk = 0; kk < 2; ++kk) {
      bf16x8 qv = *(const bf16x8*)(base + (size_t)(q16 + lr) * RS + h * 64 + kk * 32 + lh * 8);
#pragma unroll
      for (int j = 0; j < 8; ++j) qf[kk][j] = (bf16)((float)qv[j] * SM_SCALE);
    }

    float mq = -__builtin_inff(), lq = 0.f;   // softmax state for q = lr
    f32x4 o[4] = {};

    __syncthreads();  // previous item's readers done before overwrite
    STAGE(0, 0);
    __syncthreads();  // vmcnt(0) drained by compiler before barrier

    int buf = 0;
    for (int kt = 0; kt <= J; ++kt) {
      const bf16* kb = &lds_k[buf][0];
      const bf16* vb = &lds_vt[buf][0];
      if (kt < J) STAGE(buf ^ 1, kt + 1);  // async prefetch into other buf

      // ---- S^T = K (Q*scale)^T : s8[kn][r] = S[key=kn*16+lh*4+r][q=lr]
      f32x4 s8[8] = {};
      __builtin_amdgcn_s_setprio(1);
#pragma unroll
      for (int kk = 0; kk < 2; ++kk) {
#pragma unroll
        for (int kn = 0; kn < 8; ++kn) {
          const int key = kn * 16 + lr;
          bf16x8 kf = *(const bf16x8*)&kb[(key * 64 + kk * 32 + lh * 8) ^ ((key & 7) << 3)];
          s8[kn] = __builtin_amdgcn_mfma_f32_16x16x32_bf16(kf, qf[kk], s8[kn], 0, 0, 0);
        }
      }
      __builtin_amdgcn_s_setprio(0);
      // ---- causal mask (last tile only): mask key_local > q_local
      if (kt == J) {
        const int qloc = w * 16 + lr;
#pragma unroll
        for (int kn = 0; kn < 8; ++kn)
#pragma unroll
          for (int r = 0; r < 4; ++r)
            if ((kn * 16 + lh * 4 + r) > qloc) s8[kn][r] = -__builtin_inff();
      }
      // ---- online softmax: in-lane over 32 keys + 2 shfl (q = lr)
      float pm = s8[0][0];
#pragma unroll
      for (int kn = 0; kn < 8; ++kn)
#pragma unroll
        for (int r = 0; r < 4; ++r) pm = fmaxf(pm, s8[kn][r]);
      pm = fmaxf(pm, __shfl_xor(pm, 16));
      pm = fmaxf(pm, __shfl_xor(pm, 32));
      const float mnew = fmaxf(mq, pm);
      const float alpha_q = __expf(mq - mnew);
      mq = mnew;
      float ssum = 0.f;
#pragma unroll
      for (int kn = 0; kn < 8; ++kn)
#pragma unroll
        for (int r = 0; r < 4; ++r) {
          const float p2 = __expf(s8[kn][r] - mnew);
          s8[kn][r] = p2;
          ssum += p2;
        }
      ssum += __shfl_xor(ssum, 16);
      ssum += __shfl_xor(ssum, 32);
      lq = lq * alpha_q + ssum;
      // ---- rescale O (O layout: q = lh*4+r)
      float al[4];
#pragma unroll
      for (int r = 0; r < 4; ++r) al[r] = __shfl(alpha_q, lh * 4 + r);
#pragma unroll
      for (int ni = 0; ni < 4; ++ni)
#pragma unroll
        for (int r = 0; r < 4; ++r) o[ni][r] *= al[r];
      // ---- PV in two 64-key halves through the 2KB/wave P buffer
#pragma unroll
      for (int hh = 0; hh < 2; ++hh) {
#pragma unroll
        for (int kn4 = 0; kn4 < 4; ++kn4) {
          const int kn = hh * 4 + kn4;
          bf16x4 pb;
#pragma unroll
          for (int r = 0; r < 4; ++r) pb[r] = (bf16)s8[kn][r];
          *(bf16x4*)&lds_p[w][(lr * 64 + kn4 * 16 + lh * 4) ^ ((lr & 7) << 3)] = pb;
        }
        __builtin_amdgcn_s_setprio(1);
#pragma unroll
        for (int kkl = 0; kkl < 2; ++kkl) {
          bf16x8 pf = *(const bf16x8*)&lds_p[w][(lr * 64 + kkl * 32 + lh * 8) ^ ((lr & 7) << 3)];
#pragma unroll
          for (int ni = 0; ni < 4; ++ni) {
            const int d = ni * 16 + lr;
            const int key = hh * 64 + kkl * 32 + lh * 8;
            bf16x8 vf = *(const bf16x8*)&vb[d * 128 + (key ^ (vswz3(d) << 3))];
            o[ni] = __builtin_amdgcn_mfma_f32_16x16x32_bf16(pf, vf, o[ni], 0, 0, 0);
          }
        }
        __builtin_amdgcn_s_setprio(0);
      }

      if (kt < J) {   // barrier drains prefetch (vmcnt(0) at s_barrier), swap
        __syncthreads();
        buf ^= 1;
      }
    }
    // ---- epilogue: reciprocal of lsum for O's q-rows, store [B*T][C]
    float lrec[4];
#pragma unroll
    for (int r = 0; r < 4; ++r) lrec[r] = 1.0f / __shfl(lq, lh * 4 + r);
#pragma unroll
    for (int ni = 0; ni < 4; ++ni)
#pragma unroll
      for (int r = 0; r < 4; ++r) {
        const int qrow = q16 + lh * 4 + r;
        op[(size_t)qrow * C + ni * 16 + lr] = (bf16)(o[ni][r] * lrec[r]);
      }
  }
}

// ---------------------------------------------------------------------------
extern "C" void kernel_launch(void* const* d_in, const int* in_sizes, int n_in,
                              void* d_out, int out_size, void* d_ws, size_t ws_size,
                              hipStream_t stream) {
  const float* x     = (const float*)d_in[0];
  const float* Wqkv  = (const float*)d_in[1];
  const float* bqkv  = (const float*)d_in[2];
  const float* Wproj = (const float*)d_in[3];
  const float* bproj = (const float*)d_in[4];
  float* out = (float*)d_out;

  char* ws = (char*)d_ws;
  bf16* qk       = (bf16*)(ws);             // 8192*2048*2 = 33554432 B (Q,K)
  bf16* vt       = (bf16*)(ws + 33554432);  // 64*64*2048*2 = 16777216 B (V^T)
  bf16* wqkvt    = (bf16*)(ws + 50331648);  // 3072*1024*2 =  6291456 B
  bf16* wprojt   = (bf16*)(ws + 56623104);  // 1024*1024*2 =  2097152 B
  bf16* attn_out = (bf16*)(ws + 58720256);  // 8192*1024*2 = 16777216 B (total 72 MiB)
  bf16* x_bf16   = attn_out;  // aliased: x_bf16 dead before attn writes attn_out

  convert_kernel<<<dim3(M * C / (256 * 8)), 256, 0, stream>>>(x, x_bf16);
  transpose_conv_kernel<<<dim3(N1 / 32, C / 32), 256, 0, stream>>>(Wqkv, wqkvt, C, N1);
  transpose_conv_kernel<<<dim3(C / 32, C / 32), 256, 0, stream>>>(Wproj, wprojt, C, C);
  // QKV projection: Q,K -> qk[M][2C]; V -> vt[b][h][d][t]
  gemm_kernel<true, true><<<dim3(M / 128, N1 / 128), 256, 0, stream>>>(
      x_bf16, wqkvt, bqkv, qk, vt, 2 * C, C);
  attn_kernel<<<dim3(Bsz * H * 8), 512, 0, stream>>>(qk, vt, attn_out);
  gemm_kernel<false, false><<<dim3(M / 128, C / 128), 256, 0, stream>>>(
      attn_out, wprojt, bproj, out, nullptr, C, C);
}

// Round 9
// 283.720 us; speedup vs baseline: 1.0847x; 1.0289x over previous
//
#include <hip/hip_runtime.h>
#include <hip/hip_bf16.h>

typedef __bf16 bf16;
typedef __bf16 bf16x4 __attribute__((ext_vector_type(4)));
typedef __bf16 bf16x8 __attribute__((ext_vector_type(8)));
typedef float  f32x4  __attribute__((ext_vector_type(4)));

#define DEV static __device__ __forceinline__

static constexpr int Bsz = 4, T = 2048, C = 1024, H = 16;
static constexpr int M  = Bsz * T;   // 8192
static constexpr int N1 = 3 * C;     // 3072
static constexpr float SM_SCALE = 0.125f;  // D^-0.5 = 2^-3, exact in bf16

// async global->LDS, 16B per lane. LDS dest: wave-uniform base + lane*16B;
// global source address is PER-LANE (enables pre-swizzled sources, m173).
DEV void gload16(const bf16* g, const bf16* l) {
  __builtin_amdgcn_global_load_lds(
      (const __attribute__((address_space(1))) void*)g,
      (__attribute__((address_space(3))) void*)l, 16, 0, 0);
}

// ---------------------------------------------------------------------------
// fp32 -> bf16 convert (vectorized, memory-bound)
// ---------------------------------------------------------------------------
__launch_bounds__(256)
__global__ void convert_kernel(const float* __restrict__ in, bf16* __restrict__ out) {
  const size_t i = ((size_t)blockIdx.x * 256 + threadIdx.x) * 8;
  f32x4 a = *(const f32x4*)(in + i);
  f32x4 b = *(const f32x4*)(in + i + 4);
  *(bf16x4*)(out + i)     = __builtin_convertvector(a, bf16x4);
  *(bf16x4*)(out + i + 4) = __builtin_convertvector(b, bf16x4);
}

// ---------------------------------------------------------------------------
// Transpose + fp32->bf16 convert:  in[K][N] (fp32) -> out[N][K] (bf16)
// ---------------------------------------------------------------------------
__launch_bounds__(256)
__global__ void transpose_conv_kernel(const float* __restrict__ in,
                                      bf16* __restrict__ out, int K, int N) {
  __shared__ float t[32][33];
  const int n0 = blockIdx.x * 32, k0 = blockIdx.y * 32;
  const int tx = threadIdx.x & 31, ty = threadIdx.x >> 5;  // ty in 0..7
#pragma unroll
  for (int j = 0; j < 4; ++j)
    t[ty + j * 8][tx] = in[(size_t)(k0 + ty + j * 8) * N + n0 + tx];
  __syncthreads();
#pragma unroll
  for (int j = 0; j < 4; ++j)
    out[(size_t)(n0 + ty + j * 8) * K + k0 + tx] = (bf16)t[tx][ty + j * 8];
}

// ---------------------------------------------------------------------------
// GEMM, 8-wave deep-pipelined (T3/T4): Out = A @ Bt^T + bias.
// Tile 128m x 256n x BK=64. 512 thr = 8 waves (2m x 4n), wave owns 64x64,
// acc[4][4]. LDS: 3-deep rotation (A 16KB + B 32KB per tile = 144KB total).
// Schedule: while computing tile t (64 MFMA/wave, no drain), tile t+2's
// 6 gload16/thread are in flight; at tile end s_waitcnt vmcnt(6) waits only
// tile t+1's loads (counted, never 0 in main loop) then raw s_barrier.
// Chunk-XOR swizzle c^=(row&7) on frag reads; staging sources inverse-
// swizzled (rule 21 both-sides; same family as the verified attn staging).
// V_SPLIT (GEMM1): cols >= 2C go transposed to vt[b][h][d][t].
// ---------------------------------------------------------------------------
template <bool OUT_BF16, bool V_SPLIT>
__launch_bounds__(512, 1)
__global__ void gemm8_kernel(const bf16* __restrict__ A,
                             const bf16* __restrict__ Bt,
                             const float* __restrict__ bias,
                             void* __restrict__ Out, bf16* __restrict__ vt,
                             int Ndim, int Kdim) {
  __shared__ bf16 ldsA[3][128 * 64];  // 3 x 16 KB
  __shared__ bf16 ldsB[3][256 * 64];  // 3 x 32 KB
  const int tid = threadIdx.x, l = tid & 63, w = tid >> 6;
  const int wm = w >> 2, wn = w & 3;
  const int lr = l & 15, lh = l >> 4;
  const int m0 = blockIdx.x * 128, n0 = blockIdx.y * 256;
  const int rA = tid >> 3, cA = tid & 7;       // staging row-group / chunk
  const int cs = cA ^ (rA & 7);                // inverse-swizzled src chunk

  auto STAGE = [&](int nb, int t) {
    const int k0 = t * 64;
#pragma unroll
    for (int i = 0; i < 2; ++i) {  // A: 128 rows
      const int row = i * 64 + rA;
      gload16(A + (size_t)(m0 + row) * Kdim + k0 + cs * 8,
              &ldsA[nb][i * 4096 + w * 512]);
    }
#pragma unroll
    for (int i = 0; i < 4; ++i) {  // B: 256 rows
      const int row = i * 64 + rA;
      gload16(Bt + (size_t)(n0 + row) * Kdim + k0 + cs * 8,
              &ldsB[nb][i * 4096 + w * 512]);
    }
  };

  f32x4 acc[4][4] = {};
  const int NT = Kdim >> 6;  // 16 for K=1024

  STAGE(0, 0);
  STAGE(1, 1);
  asm volatile("s_waitcnt vmcnt(6)" ::: "memory");  // tile 0 landed
  __builtin_amdgcn_sched_barrier(0);
  __builtin_amdgcn_s_barrier();
  __builtin_amdgcn_sched_barrier(0);

  for (int t = 0; t < NT; ++t) {
    const int cur = t % 3;
    const bool more = (t + 2) < NT;
    if (more) STAGE((t + 2) % 3, t + 2);
    __builtin_amdgcn_sched_barrier(0);

    const bf16* a_ = &ldsA[cur][0];
    const bf16* b_ = &ldsB[cur][0];
    bf16x8 af[2][4], bfm[2][4];
#pragma unroll
    for (int kk = 0; kk < 2; ++kk) {
#pragma unroll
      for (int mi = 0; mi < 4; ++mi) {
        const int row = wm * 64 + mi * 16 + lr;
        af[kk][mi] = *(const bf16x8*)&a_[row * 64 + (((kk * 4 + lh) ^ (row & 7)) << 3)];
      }
#pragma unroll
      for (int ni = 0; ni < 4; ++ni) {
        const int row = wn * 64 + ni * 16 + lr;
        bfm[kk][ni] = *(const bf16x8*)&b_[row * 64 + (((kk * 4 + lh) ^ (row & 7)) << 3)];
      }
    }
    __builtin_amdgcn_s_setprio(1);
#pragma unroll
    for (int kk = 0; kk < 2; ++kk)
#pragma unroll
      for (int mi = 0; mi < 4; ++mi)
#pragma unroll
        for (int ni = 0; ni < 4; ++ni)
          acc[mi][ni] = __builtin_amdgcn_mfma_f32_16x16x32_bf16(
              af[kk][mi], bfm[kk][ni], acc[mi][ni], 0, 0, 0);
    __builtin_amdgcn_s_setprio(0);
    __builtin_amdgcn_sched_barrier(0);

    if (t + 1 < NT) {
      if (more) {                 // keep t+2's 6 loads in flight (counted)
        asm volatile("s_waitcnt vmcnt(6)" ::: "memory");
      } else {                    // last prefetched tile: full drain
        asm volatile("s_waitcnt vmcnt(0)" ::: "memory");
      }
      __builtin_amdgcn_sched_barrier(0);
      __builtin_amdgcn_s_barrier();
      __builtin_amdgcn_sched_barrier(0);
    }
  }

  // ---- epilogue
  if (V_SPLIT && n0 >= 2 * C) {
    const int b = m0 >> 11, tb = (m0 & 2047) + wm * 64;
#pragma unroll
    for (int ni = 0; ni < 4; ++ni) {
      const int col = n0 - 2 * C + wn * 64 + ni * 16 + lr;  // 0..1023
      const int hh = col >> 6, dd = col & 63;
      const float bv = bias[2 * C + col];
      bf16* vdst = vt + ((size_t)((b * H + hh) * 64 + dd)) * T + tb + lh * 4;
#pragma unroll
      for (int mi = 0; mi < 4; ++mi) {
        bf16x4 p4;
#pragma unroll
        for (int r = 0; r < 4; ++r) p4[r] = (bf16)(acc[mi][ni][r] + bv);
        *(bf16x4*)&vdst[mi * 16] = p4;
      }
    }
  } else {
#pragma unroll
    for (int ni = 0; ni < 4; ++ni) {
      const int col = n0 + wn * 64 + ni * 16 + lr;
      const float bv = bias[col];
#pragma unroll
      for (int mi = 0; mi < 4; ++mi) {
#pragma unroll
        for (int r = 0; r < 4; ++r) {
          const int row = m0 + wm * 64 + mi * 16 + lh * 4 + r;
          const float v = acc[mi][ni][r] + bv;
          if (OUT_BF16)
            ((bf16*)Out)[(size_t)row * Ndim + col] = (bf16)v;
          else
            ((float*)Out)[(size_t)row * Ndim + col] = v;
        }
      }
    }
  }
}

// ---------------------------------------------------------------------------
// Flash attention (causal), KVBLK=128, Q-block=128, 8 waves — UNCHANGED from
// round 8 (93 us, verified). Swapped QK^T softmax; balanced persistent grid.
// ---------------------------------------------------------------------------
DEV int vswz3(int d) { return (d & 7) ^ ((d >> 3) & 7); }

__launch_bounds__(512, 4)
__global__ void attn_kernel(const bf16* __restrict__ qk,
                            const bf16* __restrict__ vt,
                            bf16* __restrict__ out) {
  __shared__ bf16 lds_k[2][128 * 64];   // 32 KB
  __shared__ bf16 lds_vt[2][64 * 128];  // 32 KB
  __shared__ bf16 lds_p[8][16 * 64];    // 16 KB
  const int tid = threadIdx.x, l = tid & 63, w = tid >> 6;  // w: 0..7
  const int lr = l & 15, lh = l >> 4;
  const int p = blockIdx.x;
  const int bh = p >> 3, jj = p & 7;
  const int b = bh >> 4, h = bh & 15;
  const size_t RS = 2 * C;  // qk row stride (elems)
  const bf16* base  = qk + (size_t)b * T * RS;
  const bf16* kbase = base + C + h * 64;
  const bf16* vth   = vt + (size_t)bh * 64 * T;
  bf16* op = out + (size_t)b * T * C + h * 64;
  const int r1 = tid >> 3, cc = tid & 7;   // K: row group, chunk
  const int kc = cc ^ (r1 & 7);            // K source chunk (inv-swizzle)
  const int dV = tid >> 4, cV = tid & 15;  // V: d group, chunk (16/row)

  auto STAGE = [&](int nb, int kt) {
#pragma unroll
    for (int i = 0; i < 2; ++i) {
      const int rowK = i * 64 + r1;
      gload16(kbase + (size_t)(kt * 128 + rowK) * RS + kc * 8,
              &lds_k[nb][i * 4096 + w * 512]);
      const int d = i * 32 + dV;
      const int vc = (cV & 8) | (((cV & 7) ^ vswz3(d)) & 7);
      gload16(vth + (size_t)d * T + kt * 128 + vc * 8,
              &lds_vt[nb][i * 4096 + w * 512]);
    }
  };

  for (int it = 0; it < 2; ++it) {
    const int J = it ? jj : 15 - jj;   // long item first
    const int q16 = J * 128 + w * 16;
    bf16x8 qf[2];
#pragma unroll
    for (int kk = 0; kk < 2; ++kk) {
      bf16x8 qv = *(const bf16x8*)(base + (size_t)(q16 + lr) * RS + h * 64 + kk * 32 + lh * 8);
#pragma unroll
      for (int j = 0; j < 8; ++j) qf[kk][j] = (bf16)((float)qv[j] * SM_SCALE);
    }

    float mq = -__builtin_inff(), lq = 0.f;   // softmax state for q = lr
    f32x4 o[4] = {};

    __syncthreads();  // previous item's readers done before overwrite
    STAGE(0, 0);
    __syncthreads();  // vmcnt(0) drained by compiler before barrier

    int buf = 0;
    for (int kt = 0; kt <= J; ++kt) {
      const bf16* kb = &lds_k[buf][0];
      const bf16* vb = &lds_vt[buf][0];
      if (kt < J) STAGE(buf ^ 1, kt + 1);  // async prefetch into other buf

      f32x4 s8[8] = {};
      __builtin_amdgcn_s_setprio(1);
#pragma unroll
      for (int kk = 0; kk < 2; ++kk) {
#pragma unroll
        for (int kn = 0; kn < 8; ++kn) {
          const int key = kn * 16 + lr;
          bf16x8 kf = *(const bf16x8*)&kb[(key * 64 + kk * 32 + lh * 8) ^ ((key & 7) << 3)];
          s8[kn] = __builtin_amdgcn_mfma_f32_16x16x32_bf16(kf, qf[kk], s8[kn], 0, 0, 0);
        }
      }
      __builtin_amdgcn_s_setprio(0);
      if (kt == J) {
        const int qloc = w * 16 + lr;
#pragma unroll
        for (int kn = 0; kn < 8; ++kn)
#pragma unroll
          for (int r = 0; r < 4; ++r)
            if ((kn * 16 + lh * 4 + r) > qloc) s8[kn][r] = -__builtin_inff();
      }
      float pm = s8[0][0];
#pragma unroll
      for (int kn = 0; kn < 8; ++kn)
#pragma unroll
        for (int r = 0; r < 4; ++r) pm = fmaxf(pm, s8[kn][r]);
      pm = fmaxf(pm, __shfl_xor(pm, 16));
      pm = fmaxf(pm, __shfl_xor(pm, 32));
      const float mnew = fmaxf(mq, pm);
      const float alpha_q = __expf(mq - mnew);
      mq = mnew;
      float ssum = 0.f;
#pragma unroll
      for (int kn = 0; kn < 8; ++kn)
#pragma unroll
        for (int r = 0; r < 4; ++r) {
          const float p2 = __expf(s8[kn][r] - mnew);
          s8[kn][r] = p2;
          ssum += p2;
        }
      ssum += __shfl_xor(ssum, 16);
      ssum += __shfl_xor(ssum, 32);
      lq = lq * alpha_q + ssum;
      float al[4];
#pragma unroll
      for (int r = 0; r < 4; ++r) al[r] = __shfl(alpha_q, lh * 4 + r);
#pragma unroll
      for (int ni = 0; ni < 4; ++ni)
#pragma unroll
        for (int r = 0; r < 4; ++r) o[ni][r] *= al[r];
#pragma unroll
      for (int hh = 0; hh < 2; ++hh) {
#pragma unroll
        for (int kn4 = 0; kn4 < 4; ++kn4) {
          const int kn = hh * 4 + kn4;
          bf16x4 pb;
#pragma unroll
          for (int r = 0; r < 4; ++r) pb[r] = (bf16)s8[kn][r];
          *(bf16x4*)&lds_p[w][(lr * 64 + kn4 * 16 + lh * 4) ^ ((lr & 7) << 3)] = pb;
        }
        __builtin_amdgcn_s_setprio(1);
#pragma unroll
        for (int kkl = 0; kkl < 2; ++kkl) {
          bf16x8 pf = *(const bf16x8*)&lds_p[w][(lr * 64 + kkl * 32 + lh * 8) ^ ((lr & 7) << 3)];
#pragma unroll
          for (int ni = 0; ni < 4; ++ni) {
            const int d = ni * 16 + lr;
            const int key = hh * 64 + kkl * 32 + lh * 8;
            bf16x8 vf = *(const bf16x8*)&vb[d * 128 + (key ^ (vswz3(d) << 3))];
            o[ni] = __builtin_amdgcn_mfma_f32_16x16x32_bf16(pf, vf, o[ni], 0, 0, 0);
          }
        }
        __builtin_amdgcn_s_setprio(0);
      }

      if (kt < J) {
        __syncthreads();
        buf ^= 1;
      }
    }
    float lrec[4];
#pragma unroll
    for (int r = 0; r < 4; ++r) lrec[r] = 1.0f / __shfl(lq, lh * 4 + r);
#pragma unroll
    for (int ni = 0; ni < 4; ++ni)
#pragma unroll
      for (int r = 0; r < 4; ++r) {
        const int qrow = q16 + lh * 4 + r;
        op[(size_t)qrow * C + ni * 16 + lr] = (bf16)(o[ni][r] * lrec[r]);
      }
  }
}

// ---------------------------------------------------------------------------
extern "C" void kernel_launch(void* const* d_in, const int* in_sizes, int n_in,
                              void* d_out, int out_size, void* d_ws, size_t ws_size,
                              hipStream_t stream) {
  const float* x     = (const float*)d_in[0];
  const float* Wqkv  = (const float*)d_in[1];
  const float* bqkv  = (const float*)d_in[2];
  const float* Wproj = (const float*)d_in[3];
  const float* bproj = (const float*)d_in[4];
  float* out = (float*)d_out;

  char* ws = (char*)d_ws;
  bf16* qk       = (bf16*)(ws);             // 8192*2048*2 = 33554432 B (Q,K)
  bf16* vt       = (bf16*)(ws + 33554432);  // 64*64*2048*2 = 16777216 B (V^T)
  bf16* wqkvt    = (bf16*)(ws + 50331648);  // 3072*1024*2 =  6291456 B
  bf16* wprojt   = (bf16*)(ws + 56623104);  // 1024*1024*2 =  2097152 B
  bf16* attn_out = (bf16*)(ws + 58720256);  // 8192*1024*2 = 16777216 B (total 72 MiB)
  bf16* x_bf16   = attn_out;  // aliased: x_bf16 dead before attn writes attn_out

  convert_kernel<<<dim3(M * C / (256 * 8)), 256, 0, stream>>>(x, x_bf16);
  transpose_conv_kernel<<<dim3(N1 / 32, C / 32), 256, 0, stream>>>(Wqkv, wqkvt, C, N1);
  transpose_conv_kernel<<<dim3(C / 32, C / 32), 256, 0, stream>>>(Wproj, wprojt, C, C);
  // QKV projection: Q,K -> qk[M][2C]; V -> vt[b][h][d][t]
  gemm8_kernel<true, true><<<dim3(M / 128, N1 / 256), 512, 0, stream>>>(
      x_bf16, wqkvt, bqkv, qk, vt, 2 * C, C);
  attn_kernel<<<dim3(Bsz * H * 8), 512, 0, stream>>>(qk, vt, attn_out);
  gemm8_kernel<false, false><<<dim3(M / 128, C / 256), 512, 0, stream>>>(
      attn_out, wprojt, bproj, out, nullptr, C, C);
}

// Round 10
// 280.735 us; speedup vs baseline: 1.0962x; 1.0106x over previous
//
#include <hip/hip_runtime.h>
#include <hip/hip_bf16.h>

typedef __bf16 bf16;
typedef __bf16 bf16x4 __attribute__((ext_vector_type(4)));
typedef __bf16 bf16x8 __attribute__((ext_vector_type(8)));
typedef float  f32x4  __attribute__((ext_vector_type(4)));

#define DEV static __device__ __forceinline__

static constexpr int Bsz = 4, T = 2048, C = 1024, H = 16;
static constexpr int M  = Bsz * T;   // 8192
static constexpr int N1 = 3 * C;     // 3072
static constexpr float SM_SCALE = 0.125f;  // D^-0.5 = 2^-3, exact in bf16

// async global->LDS, 16B per lane. LDS dest: wave-uniform base + lane*16B;
// global source address is PER-LANE (enables pre-swizzled sources, m173).
DEV void gload16(const bf16* g, const bf16* l) {
  __builtin_amdgcn_global_load_lds(
      (const __attribute__((address_space(1))) void*)g,
      (__attribute__((address_space(3))) void*)l, 16, 0, 0);
}

// ---------------------------------------------------------------------------
// Fused preprocessing: one launch does
//   blocks [0,4096):      x fp32 -> bf16 (vectorized)
//   blocks [4096,7168):   Wqkv [K][N1] -> wqkvt [N1][K] bf16
//   blocks [7168,8192):   Wproj [K][C] -> wprojt [C][K] bf16
// ---------------------------------------------------------------------------
__launch_bounds__(256)
__global__ void prep_kernel(const float* __restrict__ x,
                            const float* __restrict__ Wqkv,
                            const float* __restrict__ Wproj,
                            bf16* __restrict__ xb,
                            bf16* __restrict__ wqkvt,
                            bf16* __restrict__ wprojt) {
  __shared__ float t[32][33];
  const int bid = blockIdx.x, tid = threadIdx.x;
  if (bid < 4096) {
    const size_t i = ((size_t)bid * 256 + tid) * 8;
    f32x4 a = *(const f32x4*)(x + i);
    f32x4 b = *(const f32x4*)(x + i + 4);
    *(bf16x4*)(xb + i)     = __builtin_convertvector(a, bf16x4);
    *(bf16x4*)(xb + i + 4) = __builtin_convertvector(b, bf16x4);
    return;
  }
  const float* in;
  bf16* out;
  int N, n0, k0;
  if (bid < 7168) {
    const int b2 = bid - 4096;
    in = Wqkv; out = wqkvt; N = N1; n0 = (b2 % 96) * 32; k0 = (b2 / 96) * 32;
  } else {
    const int b3 = bid - 7168;
    in = Wproj; out = wprojt; N = C; n0 = (b3 % 32) * 32; k0 = (b3 / 32) * 32;
  }
  const int tx = tid & 31, ty = tid >> 5;  // ty in 0..7
#pragma unroll
  for (int j = 0; j < 4; ++j)
    t[ty + j * 8][tx] = in[(size_t)(k0 + ty + j * 8) * N + n0 + tx];
  __syncthreads();
#pragma unroll
  for (int j = 0; j < 4; ++j)
    out[(size_t)(n0 + ty + j * 8) * C + k0 + tx] = (bf16)t[tx][ty + j * 8];
}

// ---------------------------------------------------------------------------
// GEMM, 8-wave pipelined, BK=32, 3-deep LDS rotation (72 KB -> 2 blocks/CU,
// 4 waves/SIMD): counted vmcnt AND cross-block overlap (round-9's 144KB
// variant had 1 block/CU -> latency-starved at 2 waves/SIMD).
// Tile 128m x 256n; wave (2m x 4n) owns 64x64, acc[4][4]; 16 MFMA + 8
// ds_read_b128 per K-tile; 3 gload16/thread/tile (A 1, B 2).
// At tile end: s_waitcnt vmcnt(3) (drains t+1, keeps t+2 in flight), barrier.
// LDS chunk swizzle c ^= (row>>1)&3 -> 2-way (free) frag reads; staging
// sources inverse-swizzled (rule 21 both-sides).
// V_SPLIT (GEMM1): cols >= 2C go transposed to vt[b][h][d][t].
// ---------------------------------------------------------------------------
template <bool OUT_BF16, bool V_SPLIT>
__launch_bounds__(512, 4)
__global__ void gemm8_kernel(const bf16* __restrict__ A,
                             const bf16* __restrict__ Bt,
                             const float* __restrict__ bias,
                             void* __restrict__ Out, bf16* __restrict__ vt,
                             int Ndim, int Kdim) {
  __shared__ bf16 ldsA[3][128 * 32];  // 3 x 8 KB
  __shared__ bf16 ldsB[3][256 * 32];  // 3 x 16 KB
  const int tid = threadIdx.x, l = tid & 63, w = tid >> 6;
  const int wm = w >> 2, wn = w & 3;
  const int lr = l & 15, lh = l >> 4;
  const int m0 = blockIdx.x * 128, n0 = blockIdx.y * 256;
  // staging: slot s covers (row = s>>2, chunk-slot = s&3); source chunk is
  // inverse-swizzled: cs = (s&3) ^ ((s>>3)&3)  (same formula for A, B0, B1)
  const int rS = tid >> 2;
  const int cs = (tid & 3) ^ ((tid >> 3) & 3);
  const int fswz = (lr >> 1) & 3;  // frag-read chunk swizzle (row>>1)&3

  auto STAGE = [&](int nb, int t) {
    const int k0 = t * 32;
    gload16(A  + (size_t)(m0 + rS) * Kdim + k0 + cs * 8, &ldsA[nb][w * 512]);
    gload16(Bt + (size_t)(n0 + rS) * Kdim + k0 + cs * 8, &ldsB[nb][w * 512]);
    gload16(Bt + (size_t)(n0 + 128 + rS) * Kdim + k0 + cs * 8,
            &ldsB[nb][4096 + w * 512]);
  };

  f32x4 acc[4][4] = {};
  const int NT = Kdim >> 5;  // 32 for K=1024

  STAGE(0, 0);
  STAGE(1, 1);
  asm volatile("s_waitcnt vmcnt(3)" ::: "memory");  // tile 0 landed
  __builtin_amdgcn_sched_barrier(0);
  __builtin_amdgcn_s_barrier();
  __builtin_amdgcn_sched_barrier(0);

  for (int t = 0; t < NT; ++t) {
    const int cur = t % 3;
    const bool more = (t + 2) < NT;
    if (more) STAGE((t + 2) % 3, t + 2);
    __builtin_amdgcn_sched_barrier(0);

    const bf16* a_ = &ldsA[cur][0];
    const bf16* b_ = &ldsB[cur][0];
    bf16x8 af[4], bfm[4];
#pragma unroll
    for (int mi = 0; mi < 4; ++mi) {
      const int row = wm * 64 + mi * 16 + lr;
      af[mi] = *(const bf16x8*)&a_[row * 32 + ((lh ^ fswz) << 3)];
    }
#pragma unroll
    for (int ni = 0; ni < 4; ++ni) {
      const int row = wn * 64 + ni * 16 + lr;
      bfm[ni] = *(const bf16x8*)&b_[row * 32 + ((lh ^ fswz) << 3)];
    }
    __builtin_amdgcn_s_setprio(1);
#pragma unroll
    for (int mi = 0; mi < 4; ++mi)
#pragma unroll
      for (int ni = 0; ni < 4; ++ni)
        acc[mi][ni] = __builtin_amdgcn_mfma_f32_16x16x32_bf16(
            af[mi], bfm[ni], acc[mi][ni], 0, 0, 0);
    __builtin_amdgcn_s_setprio(0);
    __builtin_amdgcn_sched_barrier(0);

    if (t + 1 < NT) {
      if (more) {                 // keep t+2's 3 loads in flight (counted)
        asm volatile("s_waitcnt vmcnt(3)" ::: "memory");
      } else {                    // last prefetched tile: full drain
        asm volatile("s_waitcnt vmcnt(0)" ::: "memory");
      }
      __builtin_amdgcn_sched_barrier(0);
      __builtin_amdgcn_s_barrier();
      __builtin_amdgcn_sched_barrier(0);
    }
  }

  // ---- epilogue
  if (V_SPLIT && n0 >= 2 * C) {
    const int b = m0 >> 11, tb = (m0 & 2047) + wm * 64;
#pragma unroll
    for (int ni = 0; ni < 4; ++ni) {
      const int col = n0 - 2 * C + wn * 64 + ni * 16 + lr;  // 0..1023
      const int hh = col >> 6, dd = col & 63;
      const float bv = bias[2 * C + col];
      bf16* vdst = vt + ((size_t)((b * H + hh) * 64 + dd)) * T + tb + lh * 4;
#pragma unroll
      for (int mi = 0; mi < 4; ++mi) {
        bf16x4 p4;
#pragma unroll
        for (int r = 0; r < 4; ++r) p4[r] = (bf16)(acc[mi][ni][r] + bv);
        *(bf16x4*)&vdst[mi * 16] = p4;
      }
    }
  } else {
#pragma unroll
    for (int ni = 0; ni < 4; ++ni) {
      const int col = n0 + wn * 64 + ni * 16 + lr;
      const float bv = bias[col];
#pragma unroll
      for (int mi = 0; mi < 4; ++mi) {
#pragma unroll
        for (int r = 0; r < 4; ++r) {
          const int row = m0 + wm * 64 + mi * 16 + lh * 4 + r;
          const float v = acc[mi][ni][r] + bv;
          if (OUT_BF16)
            ((bf16*)Out)[(size_t)row * Ndim + col] = (bf16)v;
          else
            ((float*)Out)[(size_t)row * Ndim + col] = v;
        }
      }
    }
  }
}

// ---------------------------------------------------------------------------
// Flash attention (causal), KVBLK=128, Q-block=128, 8 waves — UNCHANGED from
// round 8/9 (93-97 us, verified). Swapped QK^T softmax; balanced grid.
// ---------------------------------------------------------------------------
DEV int vswz3(int d) { return (d & 7) ^ ((d >> 3) & 7); }

__launch_bounds__(512, 4)
__global__ void attn_kernel(const bf16* __restrict__ qk,
                            const bf16* __restrict__ vt,
                            bf16* __restrict__ out) {
  __shared__ bf16 lds_k[2][128 * 64];   // 32 KB
  __shared__ bf16 lds_vt[2][64 * 128];  // 32 KB
  __shared__ bf16 lds_p[8][16 * 64];    // 16 KB
  const int tid = threadIdx.x, l = tid & 63, w = tid >> 6;  // w: 0..7
  const int lr = l & 15, lh = l >> 4;
  const int p = blockIdx.x;
  const int bh = p >> 3, jj = p & 7;
  const int b = bh >> 4, h = bh & 15;
  const size_t RS = 2 * C;  // qk row stride (elems)
  const bf16* base  = qk + (size_t)b * T * RS;
  const bf16* kbase = base + C + h * 64;
  const bf16* vth   = vt + (size_t)bh * 64 * T;
  bf16* op = out + (size_t)b * T * C + h * 64;
  const int r1 = tid >> 3, cc = tid & 7;   // K: row group, chunk
  const int kc = cc ^ (r1 & 7);            // K source chunk (inv-swizzle)
  const int dV = tid >> 4, cV = tid & 15;  // V: d group, chunk (16/row)

  auto STAGE = [&](int nb, int kt) {
#pragma unroll
    for (int i = 0; i < 2; ++i) {
      const int rowK = i * 64 + r1;
      gload16(kbase + (size_t)(kt * 128 + rowK) * RS + kc * 8,
              &lds_k[nb][i * 4096 + w * 512]);
      const int d = i * 32 + dV;
      const int vc = (cV & 8) | (((cV & 7) ^ vswz3(d)) & 7);
      gload16(vth + (size_t)d * T + kt * 128 + vc * 8,
              &lds_vt[nb][i * 4096 + w * 512]);
    }
  };

  for (int it = 0; it < 2; ++it) {
    const int J = it ? jj : 15 - jj;   // long item first
    const int q16 = J * 128 + w * 16;
    bf16x8 qf[2];
#pragma unroll
    for (int kk = 0; kk < 2; ++kk) {
      bf16x8 qv = *(const bf16x8*)(base + (size_t)(q16 + lr) * RS + h * 64 + kk * 32 + lh * 8);
#pragma unroll
      for (int j = 0; j < 8; ++j) qf[kk][j] = (bf16)((float)qv[j] * SM_SCALE);
    }

    float mq = -__builtin_inff(), lq = 0.f;   // softmax state for q = lr
    f32x4 o[4] = {};

    __syncthreads();  // previous item's readers done before overwrite
    STAGE(0, 0);
    __syncthreads();  // vmcnt(0) drained by compiler before barrier

    int buf = 0;
    for (int kt = 0; kt <= J; ++kt) {
      const bf16* kb = &lds_k[buf][0];
      const bf16* vb = &lds_vt[buf][0];
      if (kt < J) STAGE(buf ^ 1, kt + 1);  // async prefetch into other buf

      f32x4 s8[8] = {};
      __builtin_amdgcn_s_setprio(1);
#pragma unroll
      for (int kk = 0; kk < 2; ++kk) {
#pragma unroll
        for (int kn = 0; kn < 8; ++kn) {
          const int key = kn * 16 + lr;
          bf16x8 kf = *(const bf16x8*)&kb[(key * 64 + kk * 32 + lh * 8) ^ ((key & 7) << 3)];
          s8[kn] = __builtin_amdgcn_mfma_f32_16x16x32_bf16(kf, qf[kk], s8[kn], 0, 0, 0);
        }
      }
      __builtin_amdgcn_s_setprio(0);
      if (kt == J) {
        const int qloc = w * 16 + lr;
#pragma unroll
        for (int kn = 0; kn < 8; ++kn)
#pragma unroll
          for (int r = 0; r < 4; ++r)
            if ((kn * 16 + lh * 4 + r) > qloc) s8[kn][r] = -__builtin_inff();
      }
      float pm = s8[0][0];
#pragma unroll
      for (int kn = 0; kn < 8; ++kn)
#pragma unroll
        for (int r = 0; r < 4; ++r) pm = fmaxf(pm, s8[kn][r]);
      pm = fmaxf(pm, __shfl_xor(pm, 16));
      pm = fmaxf(pm, __shfl_xor(pm, 32));
      const float mnew = fmaxf(mq, pm);
      const float alpha_q = __expf(mq - mnew);
      mq = mnew;
      float ssum = 0.f;
#pragma unroll
      for (int kn = 0; kn < 8; ++kn)
#pragma unroll
        for (int r = 0; r < 4; ++r) {
          const float p2 = __expf(s8[kn][r] - mnew);
          s8[kn][r] = p2;
          ssum += p2;
        }
      ssum += __shfl_xor(ssum, 16);
      ssum += __shfl_xor(ssum, 32);
      lq = lq * alpha_q + ssum;
      float al[4];
#pragma unroll
      for (int r = 0; r < 4; ++r) al[r] = __shfl(alpha_q, lh * 4 + r);
#pragma unroll
      for (int ni = 0; ni < 4; ++ni)
#pragma unroll
        for (int r = 0; r < 4; ++r) o[ni][r] *= al[r];
#pragma unroll
      for (int hh = 0; hh < 2; ++hh) {
#pragma unroll
        for (int kn4 = 0; kn4 < 4; ++kn4) {
          const int kn = hh * 4 + kn4;
          bf16x4 pb;
#pragma unroll
          for (int r = 0; r < 4; ++r) pb[r] = (bf16)s8[kn][r];
          *(bf16x4*)&lds_p[w][(lr * 64 + kn4 * 16 + lh * 4) ^ ((lr & 7) << 3)] = pb;
        }
        __builtin_amdgcn_s_setprio(1);
#pragma unroll
        for (int kkl = 0; kkl < 2; ++kkl) {
          bf16x8 pf = *(const bf16x8*)&lds_p[w][(lr * 64 + kkl * 32 + lh * 8) ^ ((lr & 7) << 3)];
#pragma unroll
          for (int ni = 0; ni < 4; ++ni) {
            const int d = ni * 16 + lr;
            const int key = hh * 64 + kkl * 32 + lh * 8;
            bf16x8 vf = *(const bf16x8*)&vb[d * 128 + (key ^ (vswz3(d) << 3))];
            o[ni] = __builtin_amdgcn_mfma_f32_16x16x32_bf16(pf, vf, o[ni], 0, 0, 0);
          }
        }
        __builtin_amdgcn_s_setprio(0);
      }

      if (kt < J) {
        __syncthreads();
        buf ^= 1;
      }
    }
    float lrec[4];
#pragma unroll
    for (int r = 0; r < 4; ++r) lrec[r] = 1.0f / __shfl(lq, lh * 4 + r);
#pragma unroll
    for (int ni = 0; ni < 4; ++ni)
#pragma unroll
      for (int r = 0; r < 4; ++r) {
        const int qrow = q16 + lh * 4 + r;
        op[(size_t)qrow * C + ni * 16 + lr] = (bf16)(o[ni][r] * lrec[r]);
      }
  }
}

// ---------------------------------------------------------------------------
extern "C" void kernel_launch(void* const* d_in, const int* in_sizes, int n_in,
                              void* d_out, int out_size, void* d_ws, size_t ws_size,
                              hipStream_t stream) {
  const float* x     = (const float*)d_in[0];
  const float* Wqkv  = (const float*)d_in[1];
  const float* bqkv  = (const float*)d_in[2];
  const float* Wproj = (const float*)d_in[3];
  const float* bproj = (const float*)d_in[4];
  float* out = (float*)d_out;

  char* ws = (char*)d_ws;
  bf16* qk       = (bf16*)(ws);             // 8192*2048*2 = 33554432 B (Q,K)
  bf16* vt       = (bf16*)(ws + 33554432);  // 64*64*2048*2 = 16777216 B (V^T)
  bf16* wqkvt    = (bf16*)(ws + 50331648);  // 3072*1024*2 =  6291456 B
  bf16* wprojt   = (bf16*)(ws + 56623104);  // 1024*1024*2 =  2097152 B
  bf16* attn_out = (bf16*)(ws + 58720256);  // 8192*1024*2 = 16777216 B (total 72 MiB)
  bf16* x_bf16   = attn_out;  // aliased: x_bf16 dead before attn writes attn_out

  prep_kernel<<<dim3(8192), 256, 0, stream>>>(x, Wqkv, Wproj, x_bf16, wqkvt, wprojt);
  // QKV projection: Q,K -> qk[M][2C]; V -> vt[b][h][d][t]
  gemm8_kernel<true, true><<<dim3(M / 128, N1 / 256), 512, 0, stream>>>(
      x_bf16, wqkvt, bqkv, qk, vt, 2 * C, C);
  attn_kernel<<<dim3(Bsz * H * 8), 512, 0, stream>>>(qk, vt, attn_out);
  gemm8_kernel<false, false><<<dim3(M / 128, C / 256), 512, 0, stream>>>(
      attn_out, wprojt, bproj, out, nullptr, C, C);
}